// Round 7
// baseline (828.843 us; speedup 1.0000x reference)
//
#include <hip/hip_runtime.h>
#include <hip/hip_bf16.h>

#define NTOK 511
#define NINT 255

typedef unsigned short u16;
typedef __attribute__((ext_vector_type(8))) short bf16x8;
typedef __attribute__((ext_vector_type(4))) float f32x4;

// ---- workspace layout (float offsets) ----
constexpr int OFF_FLAG = 0;                 // [0] dtype flag
constexpr int OFF_WB   = 4;                 // bf16 weight region
// per jc (72 frags x 512): f 0..15 = Wx(g=f>>2,ks=f&3), 16..31 = Uu, 32..71 = Ub(g=(f-32)>>3,ks=&7)
constexpr int W3B = 294912;                 // leaf W3: [jc][ks] 8x4x512 = 16384
constexpr int WB_ELEMS = 311296;
constexpr int OFF_BIAS = OFF_WB + WB_ELEMS / 2;
constexpr int BW4 = 0, BUB4 = 512, BUB1 = 1024, BUU4 = 1152, B3 = 1664;
constexpr int BIAS_FLOATS = 1792;
constexpr int OFF_ROOT  = OFF_BIAS + BIAS_FLOATS;   // rootH 32768 + rootC 32768 (fp32)
constexpr int OFF_SYNC  = OFF_ROOT + 65536;         // 1024 uint sync counters
constexpr int OFF_CHUNK = OFF_SYNC + 1024;
constexpr long PER_TREE = 49152;            // floats: Ha bf16 + Hb bf16 + Ca f32 + Cb f32

__device__ __forceinline__ float bf2f(__hip_bfloat16 v) { return __bfloat162float(v); }
__device__ __forceinline__ short f2s(float f) {
    __hip_bfloat16 b = __float2bfloat16(f);
    return *reinterpret_cast<short*>(&b);
}
__device__ __forceinline__ float sigm(float x) { return 1.0f / (1.0f + __expf(-x)); }
__device__ __forceinline__ float tanh_(float x) { return 1.0f - 2.0f / (__expf(2.0f * x) + 1.0f); }

__device__ __forceinline__ float ldf(const void* p, long idx, int isbf) {
    return isbf ? bf2f(((const __hip_bfloat16*)p)[idx]) : ((const float*)p)[idx];
}

__device__ __forceinline__ bf16x8 ldA(const void* p, long idx, int isbf) {
    if (isbf) return *(const bf16x8*)((const short*)p + idx);
    const float* f = (const float*)p + idx;
    float4 a = *(const float4*)f, b = *(const float4*)(f + 4);
    bf16x8 r;
    r[0] = f2s(a.x); r[1] = f2s(a.y); r[2] = f2s(a.z); r[3] = f2s(a.w);
    r[4] = f2s(b.x); r[5] = f2s(b.y); r[6] = f2s(b.z); r[7] = f2s(b.w);
    return r;
}

// async global->LDS 16B
typedef const __attribute__((address_space(1))) unsigned int* gp1_t;
typedef __attribute__((address_space(3))) unsigned int* lp3_t;
__device__ __forceinline__ void stage16(const void* g, void* l) {
    __builtin_amdgcn_global_load_lds((gp1_t)g, (lp3_t)l, 16, 0, 0);
}

// manual device-scope grid barrier (co-residency guaranteed by host-side occupancy check)
__device__ __forceinline__ void gridsync(unsigned int* ctr, int NB) {
    __threadfence();            // release: drain my stores, L2 writeback
    __syncthreads();
    if (threadIdx.x == 0) {
        __hip_atomic_fetch_add(ctr, 1u, __ATOMIC_ACQ_REL, __HIP_MEMORY_SCOPE_AGENT);
        while (__hip_atomic_load(ctr, __ATOMIC_ACQUIRE, __HIP_MEMORY_SCOPE_AGENT) < (unsigned)NB)
            __builtin_amdgcn_s_sleep(8);
    }
    __syncthreads();
    __threadfence();            // acquire: invalidate L1/L2 before reading peers' data
}

// ---- dtype detection ----
__global__ void detect_kernel(const void* W, float* ws) {
    if (threadIdx.x == 0 && blockIdx.x == 0) {
        const u16* u = (const u16*)W;
        int cnt = 0;
        for (int i = 0; i < 128; i += 2) {
            u16 x = u[i];
            int ex = (x >> 7) & 0xff;
            if (x == 0 || (ex >= 96 && ex <= 127)) cnt++;
        }
        ((int*)ws)[0] = (cnt >= 48) ? 1 : 0;
    }
}

// ---- repack: raw weights -> bf16 jc-major frag-linear + fp32 biases ----
__global__ __launch_bounds__(256) void repack_mfma(
    const void* W, const void* bW, const void* Ubin, const void* bUbin,
    const void* Uun, const void* bUun, float* ws)
{
    const int isbf = ((const int*)ws)[0];
    short* wb = (short*)(ws + OFF_WB);
    float* bias = ws + OFF_BIAS;
    int tid = blockIdx.x * blockDim.x + threadIdx.x;
    int nth = gridDim.x * blockDim.x;

    for (int idx = tid; idx < 294912; idx += nth) {
        int e = idx & 511, fjc = idx >> 9;
        int jc = fjc / 72, f = fjc - jc * 72;
        int lane = e >> 3, id8 = e & 7;
        int j = jc * 16 + (lane & 15);
        float v;
        if (f < 16) {
            int g = f >> 2, ks = f & 3;
            int k = ks * 32 + (lane >> 4) * 8 + id8;
            v = ldf(W, (long)g * 16384 + k * 128 + j, isbf);
        } else if (f < 32) {
            int fu = f - 16; int g = fu >> 2, ks = fu & 3;
            int k = ks * 32 + (lane >> 4) * 8 + id8;
            v = ldf(Uun, (long)g * 16384 + k * 128 + j, isbf);
        } else {
            int fb = f - 32; int g = fb >> 3, ks = fb & 7;
            int k = ks * 32 + (lane >> 4) * 8 + id8;
            v = ldf(Ubin, (long)g * 32768 + k * 128 + j, isbf);
        }
        wb[idx] = f2s(v);
    }
    for (int idx = tid; idx < 16384; idx += nth) {
        int e = idx & 511, frag = idx >> 9;
        int jc = frag >> 2, ks = frag & 3;
        int lane = e >> 3, id8 = e & 7;
        int k = ks * 32 + (lane >> 4) * 8 + id8;
        int j = jc * 16 + (lane & 15);
        wb[W3B + idx] = f2s(ldf(W, (long)3 * 16384 + k * 128 + j, isbf));
    }
    for (int j = tid; j < 128; j += nth) {
        float4 b;
        b.x = ldf(bW, 0 * 128 + j, isbf); b.y = ldf(bW, 1 * 128 + j, isbf);
        b.z = ldf(bW, 2 * 128 + j, isbf); b.w = ldf(bW, 3 * 128 + j, isbf);
        ((float4*)(bias + BW4))[j] = b;
        float4 bb;
        bb.x = ldf(bUbin, 0 * 128 + j, isbf); bb.y = ldf(bUbin, 1 * 128 + j, isbf);
        bb.z = ldf(bUbin, 2 * 128 + j, isbf); bb.w = ldf(bUbin, 3 * 128 + j, isbf);
        ((float4*)(bias + BUB4))[j] = bb;
        (bias + BUB1)[j] = ldf(bUbin, 4 * 128 + j, isbf);
        float4 bu;
        bu.x = ldf(bUun, 0 * 128 + j, isbf); bu.y = ldf(bUun, 1 * 128 + j, isbf);
        bu.z = ldf(bUun, 2 * 128 + j, isbf); bu.w = ldf(bUun, 3 * 128 + j, isbf);
        ((float4*)(bias + BUU4))[j] = bu;
        (bias + B3)[j] = ldf(bW, 3 * 128 + j, isbf);
    }
}

#define MFMA(A, B, C) __builtin_amdgcn_mfma_f32_16x16x32_bf16(A, B, C, 0, 0, 0)

// ============================================================================
// PERSISTENT FUSED KERNEL: leaf + levels 7..0, weights staged once per block,
// manual grid barrier between levels. Grid = 8 jc x NBM m-blocks (co-resident).
// ============================================================================
__global__ __launch_bounds__(256, 2) void tree_coop(
    const int* __restrict__ tokens, const int* __restrict__ arity, const void* emb,
    float* __restrict__ ws, short* __restrict__ Ha, short* __restrict__ Hb,
    float* __restrict__ Ca, float* __restrict__ Cb,
    float* __restrict__ rootH, float* __restrict__ rootC,
    unsigned int* __restrict__ sync, int treeOff, int Bc)
{
    __shared__ short Bs[72 * 512];          // 72 KB: this jc's full weight slice
    __shared__ short hst[4][2][16][20];     // wave-private h transpose
    const int t = threadIdx.x;
    const int isbf = ((const int*)ws)[0];
    const int jc = blockIdx.x & 7;          // jc <-> XCD aligned
    const int mb = blockIdx.x >> 3;
    const int NBM = gridDim.x >> 3;
    const int NB = gridDim.x;
    const int wv = t >> 6, lane = t & 63, quad = lane >> 4, l16 = lane & 15;
    const short* wb = (const short*)(ws + OFF_WB);
    const float* bias = ws + OFF_BIAS;

    // issue the one-time weight stage; drains under the leaf phase
    const short* wsrc = wb + (long)jc * 36864;
#pragma unroll
    for (int s = 0; s < 18; ++s) {
        int off = (s * 256 + t) * 8;
        stage16(wsrc + off, &Bs[off]);
    }

    // ---- leaf phase: h = tanh(x @ W3 + b3), W3 (this jc) in registers ----
    {
        bf16x8 w3[4];
#pragma unroll
        for (int ks = 0; ks < 4; ++ks)
            w3[ks] = *(const bf16x8*)(wb + W3B + ((jc * 4 + ks) << 9) + lane * 8);
        float b3v = (bias + B3)[jc * 16 + l16];
        const int Mleaf = Bc << 8;
        const int itersL = (Mleaf + NBM * 128 - 1) / (NBM * 128);
        for (int it = 0; it < itersL; ++it) {
            int rb0 = (mb * itersL + it) * 128;
            if (rb0 >= Mleaf) break;
            int rb = rb0 + wv * 32;
            f32x4 acc[2] = {{0,0,0,0},{0,0,0,0}};
#pragma unroll
            for (int mt = 0; mt < 2; ++mt) {
                int p = rb + mt * 16 + l16; if (p >= Mleaf) p = Mleaf - 1;
                int bl = p >> 8, i = p & 255;
                int tk = tokens[(long)(treeOff + bl) * NTOK + 255 + i];
#pragma unroll
                for (int ks = 0; ks < 4; ++ks) {
                    bf16x8 a = ldA(emb, (long)tk * 128 + ks * 32 + quad * 8, isbf);
                    acc[mt] = MFMA(a, w3[ks], acc[mt]);
                }
            }
#pragma unroll
            for (int mt = 0; mt < 2; ++mt)
#pragma unroll
                for (int r = 0; r < 4; ++r)
                    hst[wv][mt][quad * 4 + r][l16] = f2s(tanh_(acc[mt][r] + b3v));
            int nloc = lane >> 2, c0 = (lane & 3) * 4;
#pragma unroll
            for (int mt = 0; mt < 2; ++mt) {
                int prow = rb + mt * 16 + nloc;
                if (prow < Mleaf) {
                    uint2 v = *(const uint2*)&hst[wv][mt][nloc][c0];
                    *(uint2*)&Ha[((long)jc * Mleaf + prow) * 16 + c0] = v;
                }
            }
        }
    }
    __syncthreads();   // weight stage drained; Bs ready

    // per-jc biases
    const int j = jc * 16 + l16;
    const float4 bw  = ((const float4*)(bias + BW4))[j];
    const float4 bbv = ((const float4*)(bias + BUB4))[j];
    const float  b1  = (bias + BUB1)[j];
    const float4 bu  = ((const float4*)(bias + BUU4))[j];

    int sidx = 0;
    gridsync(&sync[sidx++], NB);   // leaf h visible device-wide

    for (int l = 7; l >= 0; --l) {
        const int M = Bc << l, Mchild = Bc << (l + 1);
        const int cnt = 1 << l, o2 = cnt - 1;
        const short* hC = (l & 1) ? Ha : Hb;
        const float* cC = (l & 1) ? Ca : Cb;
        short* hO = (l & 1) ? Hb : Ha;
        float* cO = (l & 1) ? Cb : Ca;
        const bool leafchild = (l == 7), isRoot = (l == 0);
        const int iters = (M + NBM * 128 - 1) / (NBM * 128);

        for (int it = 0; it < iters; ++it) {
            int rb0 = (mb * iters + it) * 128;
            if (rb0 >= M) break;
            int rb = rb0 + wv * 32;

            // ---- prefetch everything latency-bound ----
            bf16x8 ax[2][4], ah[2][8];
            int arr[2][4];
            float clv[2][4], crv[2][4];
#pragma unroll
            for (int mt = 0; mt < 2; ++mt) {
                int p = rb + mt * 16 + l16; if (p >= M) p = M - 1;
                int bl = p >> l, i = p - (bl << l);
                int tk = tokens[(long)(treeOff + bl) * NTOK + o2 + i];
                long crow = (long)bl * (cnt << 1) + 2 * i;
#pragma unroll
                for (int ks = 0; ks < 4; ++ks)
                    ax[mt][ks] = ldA(emb, (long)tk * 128 + ks * 32 + quad * 8, isbf);
#pragma unroll
                for (int ks = 0; ks < 8; ++ks) {
                    int k0 = ks * 32 + quad * 8;
                    int side = k0 >> 7, kl = k0 & 127;
                    ah[mt][ks] = *(const bf16x8*)(hC +
                        ((long)(kl >> 4) * Mchild + crow + side) * 16 + (kl & 15));
                }
#pragma unroll
                for (int r = 0; r < 4; ++r) {
                    int pe = rb + mt * 16 + quad * 4 + r; if (pe >= M) pe = M - 1;
                    int ble = pe >> l, ie = pe - (ble << l);
                    arr[mt][r] = arity[(long)(treeOff + ble) * NINT + o2 + ie];
                    if (!leafchild) {
                        long crowe = (long)ble * (cnt << 1) + 2 * ie;
                        clv[mt][r] = cC[((long)jc * Mchild + crowe) * 16 + l16];
                        crv[mt][r] = cC[((long)jc * Mchild + crowe + 1) * 16 + l16];
                    } else { clv[mt][r] = 0.f; crv[mt][r] = 0.f; }
                }
            }

            // ---- MFMA phases (all from LDS-persistent Bs) ----
            f32x4 aW[4][2], aU[4][2], aB[5][2];
#pragma unroll
            for (int g = 0; g < 4; ++g) { aW[g][0] = {0,0,0,0}; aW[g][1] = {0,0,0,0};
                                          aU[g][0] = {0,0,0,0}; aU[g][1] = {0,0,0,0}; }
#pragma unroll
            for (int g = 0; g < 5; ++g) { aB[g][0] = {0,0,0,0}; aB[g][1] = {0,0,0,0}; }

#pragma unroll
            for (int f = 0; f < 16; ++f) {
                bf16x8 b = *(const bf16x8*)&Bs[f * 512 + lane * 8];
                aW[f >> 2][0] = MFMA(ax[0][f & 3], b, aW[f >> 2][0]);
                aW[f >> 2][1] = MFMA(ax[1][f & 3], b, aW[f >> 2][1]);
            }
#pragma unroll
            for (int f = 16; f < 32; ++f) {
                bf16x8 b = *(const bf16x8*)&Bs[f * 512 + lane * 8];
                int g = (f - 16) >> 2, ks = (f - 16) & 3;
                aU[g][0] = MFMA(ah[0][ks], b, aU[g][0]);
                aU[g][1] = MFMA(ah[1][ks], b, aU[g][1]);
            }
#pragma unroll
            for (int f = 32; f < 72; ++f) {
                bf16x8 b = *(const bf16x8*)&Bs[f * 512 + lane * 8];
                int g = (f - 32) >> 3, ks = (f - 32) & 7;
                aB[g][0] = MFMA(ah[0][ks], b, aB[g][0]);
                aB[g][1] = MFMA(ah[1][ks], b, aB[g][1]);
            }

            // ---- epilogue ----
#pragma unroll
            for (int mt = 0; mt < 2; ++mt) {
#pragma unroll
                for (int r = 0; r < 4; ++r) {
                    int p = rb + mt * 16 + quad * 4 + r;
                    bool val = (p < M);
                    int pc = val ? p : M - 1;
                    int bl = pc >> l, i = pc - (bl << l);
                    bool bin = (arr[mt][r] == 1);
                    float w0 = aW[0][mt][r] + bw.x;
                    float w1 = aW[1][mt][r] + bw.y;
                    float w2 = aW[2][mt][r] + bw.z;
                    float w3 = aW[3][mt][r] + bw.w;
                    float pi, pf, po, pu;
                    if (bin) { pi = w0 + aB[0][mt][r] + bbv.x; pf = w1 + aB[1][mt][r] + bbv.y;
                               po = w2 + aB[3][mt][r] + bbv.w; pu = w3 + aB[4][mt][r] + b1; }
                    else     { pi = w0 + aU[0][mt][r] + bu.x;  pf = w1 + aU[1][mt][r] + bu.y;
                               po = w2 + aU[2][mt][r] + bu.z;  pu = w3 + aU[3][mt][r] + bu.w; }
                    float cl = clv[mt][r];
                    float cr = bin ? crv[mt][r] : 0.f;
                    float frv = bin ? sigm(w1 + aB[2][mt][r] + bbv.z) : 0.f;
                    float ig = sigm(pi), fg = sigm(pf), og = sigm(po), ug = tanh_(pu);
                    float c = ig * ug + fg * cl + frv * cr;
                    float h = og * tanh_(c);
                    if (isRoot) {
                        if (val) {
                            rootH[(long)(treeOff + bl) * 128 + j] = h;
                            rootC[(long)(treeOff + bl) * 128 + j] = c;
                        }
                    } else {
                        if (val) cO[((long)jc * M + pc) * 16 + l16] = c;
                        hst[wv][mt][quad * 4 + r][l16] = f2s(h);
                    }
                }
            }
            if (!isRoot) {
                int nloc = lane >> 2, c0 = (lane & 3) * 4;
#pragma unroll
                for (int mt = 0; mt < 2; ++mt) {
                    int prow = rb + mt * 16 + nloc;
                    if (prow < M) {
                        uint2 v = *(const uint2*)&hst[wv][mt][nloc][c0];
                        *(uint2*)&hO[((long)jc * M + prow) * 16 + c0] = v;
                    }
                }
            }
        }
        if (l > 0) gridsync(&sync[sidx++], NB);
    }
}

// ============================================================================
// FALLBACK PATH (round-6): per-level kernels, used if co-residency not provable
// ============================================================================
__global__ __launch_bounds__(256, 2) void leaf_mfma(
    const int* __restrict__ tokens, const void* emb, const float* __restrict__ ws,
    short* __restrict__ hOut, int treeOff, int Mtot, int iters)
{
    __shared__ short hst[4][16][132];
    const int t = threadIdx.x;
    const int isbf = ((const int*)ws)[0];
    const int wv = t >> 6, lane = t & 63, quad = lane >> 4, l16 = lane & 15;
    const short* wb = (const short*)(ws + OFF_WB);
    const float* bias = ws + OFF_BIAS;

    bf16x8 bf[32];
#pragma unroll
    for (int f = 0; f < 32; ++f)
        bf[f] = *(const bf16x8*)(wb + W3B + f * 512 + lane * 8);
    float b3v[8];
#pragma unroll
    for (int jc = 0; jc < 8; ++jc) b3v[jc] = (bias + B3)[jc * 16 + l16];

    for (int it = 0; it < iters; ++it) {
        int rb = (blockIdx.x * iters + it) * 64 + wv * 16;
        if (rb >= Mtot) break;
        int p = rb + l16; if (p >= Mtot) p = Mtot - 1;
        int bl = p >> 8, i = p & 255;
        int tk = tokens[(long)(treeOff + bl) * NTOK + 255 + i];
        bf16x8 ax[4];
#pragma unroll
        for (int ks = 0; ks < 4; ++ks)
            ax[ks] = ldA(emb, (long)tk * 128 + ks * 32 + quad * 8, isbf);
        f32x4 acc[8];
#pragma unroll
        for (int jc = 0; jc < 8; ++jc) acc[jc] = {0.f, 0.f, 0.f, 0.f};
#pragma unroll
        for (int jc = 0; jc < 8; ++jc)
#pragma unroll
            for (int ks = 0; ks < 4; ++ks)
                acc[jc] = MFMA(ax[ks], bf[jc * 4 + ks], acc[jc]);
#pragma unroll
        for (int jc = 0; jc < 8; ++jc)
#pragma unroll
            for (int r = 0; r < 4; ++r)
                hst[wv][quad * 4 + r][jc * 16 + l16] = f2s(tanh_(acc[jc][r] + b3v[jc]));
        int nloc = lane >> 2, c0 = (lane & 3) * 4;
        int prow = rb + nloc;
        if (prow < Mtot) {
#pragma unroll
            for (int jcb = 0; jcb < 8; ++jcb) {
                uint2 v = *(const uint2*)&hst[wv][nloc][jcb * 16 + c0];
                *(uint2*)&hOut[((long)jcb * Mtot + prow) * 16 + c0] = v;
            }
        }
    }
}

template <int JCC>
__global__ __launch_bounds__(256, 2) void level_mfma(
    const int* __restrict__ tokens, const int* __restrict__ arity, const void* emb,
    const float* __restrict__ ws, const short* __restrict__ hChild,
    const float* __restrict__ cChild, short* __restrict__ hOut, float* __restrict__ cOut,
    float* __restrict__ rootH, float* __restrict__ rootC,
    int lvl, int treeOff, int leafchild, int isRoot, int Mtot, int Mchild, int NBM)
{
    __shared__ short Bs[72 * 512];
    __shared__ short hst[4][2][16][20];
    __shared__ int tok[128];
    __shared__ int ar[128];

    const int t = threadIdx.x;
    const int isbf = ((const int*)ws)[0];
    const int jsx = blockIdx.x / NBM;
    const int mb  = blockIdx.x - jsx * NBM;
    const int jcLo = jsx * JCC;
    const int p0 = mb * 128;
    const int wv = t >> 6, lane = t & 63, quad = lane >> 4, l16 = lane & 15;
    const int cnt = 1 << lvl, o2 = cnt - 1;

    if (t < 128) {
        int p = p0 + t; if (p >= Mtot) p = Mtot - 1;
        int bl = p >> lvl, i = p - (bl << lvl);
        tok[t] = tokens[(long)(treeOff + bl) * NTOK + o2 + i];
        ar[t]  = arity[(long)(treeOff + bl) * NINT + o2 + i];
    }
    __syncthreads();

    bf16x8 ax[2][4], ah[2][8];
#pragma unroll
    for (int mt = 0; mt < 2; ++mt) {
        int row = wv * 32 + mt * 16 + l16;
        int p = p0 + row; if (p >= Mtot) p = Mtot - 1;
        int bl = p >> lvl, i = p - (bl << lvl);
        long crow = (long)bl * (cnt << 1) + 2 * i;
        int tk = tok[row];
#pragma unroll
        for (int ks = 0; ks < 4; ++ks)
            ax[mt][ks] = ldA(emb, (long)tk * 128 + ks * 32 + quad * 8, isbf);
#pragma unroll
        for (int ks = 0; ks < 8; ++ks) {
            int k0 = ks * 32 + quad * 8;
            int side = k0 >> 7, kl = k0 & 127;
            ah[mt][ks] = *(const bf16x8*)(hChild +
                ((long)(kl >> 4) * Mchild + crow + side) * 16 + (kl & 15));
        }
    }

    const float* bias = ws + OFF_BIAS;
    const short* wb = (const short*)(ws + OFF_WB);

    for (int jx = 0; jx < JCC; ++jx) {
        const int jc = jcLo + jx;
        const short* wsrc = wb + (long)jc * 36864;
#pragma unroll
        for (int s = 0; s < 18; ++s) {
            int off = (s * 256 + t) * 8;
            stage16(wsrc + off, &Bs[off]);
        }
        const int j = jc * 16 + l16;
        const float4 bw = ((const float4*)(bias + BW4))[j];
        const float4 bb = ((const float4*)(bias + BUB4))[j];
        const float  b1 = (bias + BUB1)[j];
        const float4 bu = ((const float4*)(bias + BUU4))[j];
        __syncthreads();

        f32x4 aW[4][2], aU[4][2], aB[5][2];
#pragma unroll
        for (int g = 0; g < 4; ++g) { aW[g][0] = {0,0,0,0}; aW[g][1] = {0,0,0,0};
                                      aU[g][0] = {0,0,0,0}; aU[g][1] = {0,0,0,0}; }
#pragma unroll
        for (int g = 0; g < 5; ++g) { aB[g][0] = {0,0,0,0}; aB[g][1] = {0,0,0,0}; }

#pragma unroll
        for (int f = 0; f < 16; ++f) {
            bf16x8 b = *(const bf16x8*)&Bs[f * 512 + lane * 8];
            aW[f >> 2][0] = MFMA(ax[0][f & 3], b, aW[f >> 2][0]);
            aW[f >> 2][1] = MFMA(ax[1][f & 3], b, aW[f >> 2][1]);
        }
#pragma unroll
        for (int f = 16; f < 32; ++f) {
            bf16x8 b = *(const bf16x8*)&Bs[f * 512 + lane * 8];
            int g = (f - 16) >> 2, ks = (f - 16) & 3;
            aU[g][0] = MFMA(ah[0][ks], b, aU[g][0]);
            aU[g][1] = MFMA(ah[1][ks], b, aU[g][1]);
        }
#pragma unroll
        for (int f = 32; f < 72; ++f) {
            bf16x8 b = *(const bf16x8*)&Bs[f * 512 + lane * 8];
            int g = (f - 32) >> 3, ks = (f - 32) & 7;
            aB[g][0] = MFMA(ah[0][ks], b, aB[g][0]);
            aB[g][1] = MFMA(ah[1][ks], b, aB[g][1]);
        }

#pragma unroll
        for (int mt = 0; mt < 2; ++mt) {
#pragma unroll
            for (int r = 0; r < 4; ++r) {
                int ml = wv * 32 + mt * 16 + quad * 4 + r;
                int p = p0 + ml;
                bool val = (p < Mtot);
                int pc = val ? p : Mtot - 1;
                int bl = pc >> lvl, i = pc - (bl << lvl);
                bool bin = (ar[ml] == 1);
                float w0 = aW[0][mt][r] + bw.x;
                float w1 = aW[1][mt][r] + bw.y;
                float w2 = aW[2][mt][r] + bw.z;
                float w3 = aW[3][mt][r] + bw.w;
                float pi, pf, po, pu;
                if (bin) { pi = w0 + aB[0][mt][r] + bb.x; pf = w1 + aB[1][mt][r] + bb.y;
                           po = w2 + aB[3][mt][r] + bb.w; pu = w3 + aB[4][mt][r] + b1; }
                else     { pi = w0 + aU[0][mt][r] + bu.x; pf = w1 + aU[1][mt][r] + bu.y;
                           po = w2 + aU[2][mt][r] + bu.z; pu = w3 + aU[3][mt][r] + bu.w; }
                long crow = (long)bl * (cnt << 1) + 2 * i;
                float cl = 0.f, cr = 0.f, frv = 0.f;
                if (!leafchild) {
                    cl = cChild[((long)jc * Mchild + crow) * 16 + l16];
                    if (bin) cr = cChild[((long)jc * Mchild + crow + 1) * 16 + l16];
                }
                if (bin) frv = sigm(w1 + aB[2][mt][r] + bb.z);
                float ig = sigm(pi), fg = sigm(pf), og = sigm(po), ug = tanh_(pu);
                float c = ig * ug + fg * cl + frv * cr;
                float h = og * tanh_(c);
                if (isRoot) {
                    if (val) {
                        rootH[(long)(treeOff + bl) * 128 + j] = h;
                        rootC[(long)(treeOff + bl) * 128 + j] = c;
                    }
                } else {
                    if (val) cOut[((long)jc * Mtot + pc) * 16 + l16] = c;
                    hst[wv][mt][quad * 4 + r][l16] = f2s(h);
                }
            }
        }
        if (!isRoot) {
            int nloc = lane >> 2, c0 = (lane & 3) * 4;
#pragma unroll
            for (int mt = 0; mt < 2; ++mt) {
                int prow = p0 + wv * 32 + mt * 16 + nloc;
                if (prow < Mtot) {
                    uint2 v = *(const uint2*)&hst[wv][mt][nloc][c0];
                    *(uint2*)&hOut[((long)jc * Mtot + prow) * 16 + c0] = v;
                }
            }
        }
        __syncthreads();
    }
}

// ---- output: rootH/rootC fp32 -> d_out ----
__global__ __launch_bounds__(256) void out_kernel(const float* ws, void* out)
{
    const int isbf = ((const int*)ws)[0];
    const float* rootH = ws + OFF_ROOT;
    const float* rootC = rootH + 32768;
    int t = blockIdx.x * 256 + threadIdx.x;
    float h = rootH[t], c = rootC[t];
    if (isbf) {
        ((__hip_bfloat16*)out)[t]         = __float2bfloat16(h);
        ((__hip_bfloat16*)out)[32768 + t] = __float2bfloat16(c);
    } else {
        ((float*)out)[t]         = h;
        ((float*)out)[32768 + t] = c;
    }
}

extern "C" void kernel_launch(void* const* d_in, const int* in_sizes, int n_in,
                              void* d_out, int out_size, void* d_ws, size_t ws_size,
                              hipStream_t stream)
{
    const int* tokens = (const int*)d_in[0];
    const int* arity  = (const int*)d_in[1];
    const void* emb   = d_in[2];
    const void* W     = d_in[3];
    const void* bW    = d_in[4];
    const void* Ubin  = d_in[5];
    const void* bUbin = d_in[6];
    const void* Uun   = d_in[7];
    const void* bUun  = d_in[8];

    float* ws = (float*)d_ws;

    int Bc = 256;
    while (Bc > 1 && (size_t)(OFF_CHUNK + Bc * PER_TREE) * 4 > ws_size) Bc >>= 1;
    const int nCh = 256 / Bc;

    detect_kernel<<<1, 64, 0, stream>>>(W, ws);
    repack_mfma<<<128, 256, 0, stream>>>(W, bW, Ubin, bUbin, Uun, bUun, ws);

    short* Ha = (short*)(ws + OFF_CHUNK);
    short* Hb = Ha + (long)Bc * 32768;
    float* Ca = (float*)(Hb + (long)Bc * 16384);
    float* Cb = Ca + (long)Bc * 8192;
    float* rootH = ws + OFF_ROOT;
    float* rootC = rootH + 32768;
    unsigned int* syncArr = (unsigned int*)(ws + OFF_SYNC);

    // decide persistent-kernel path: need provable co-residency of the whole grid
    int occ = 0, nCU = 0, dev = 0;
    bool useCoop = false;
    if (hipGetDevice(&dev) == hipSuccess &&
        hipDeviceGetAttribute(&nCU, hipDeviceAttributeMultiprocessorCount, dev) == hipSuccess &&
        hipOccupancyMaxActiveBlocksPerMultiprocessor(&occ, tree_coop, 256, 0) == hipSuccess) {
        if (occ >= 1 && nCU >= 8) useCoop = true;
    }
    int NBM = 64;
    if (useCoop) {
        long cap = (long)nCU * occ;
        NBM = (int)(cap / 8); if (NBM > 64) NBM = 64; if (NBM < 1) { useCoop = false; }
        if (nCh * 8 > 1024) useCoop = false;   // sync counter capacity
    }

    if (useCoop) {
        hipMemsetAsync(syncArr, 0, 1024 * sizeof(unsigned int), stream);
        for (int cidx = 0; cidx < nCh; ++cidx) {
            int toff = cidx * Bc;
            tree_coop<<<dim3(8 * NBM), 256, 0, stream>>>(
                tokens, arity, emb, ws, Ha, Hb, Ca, Cb, rootH, rootC,
                syncArr + cidx * 8, toff, Bc);
        }
    } else {
        for (int cidx = 0; cidx < nCh; ++cidx) {
            int toff = cidx * Bc;
            {
                int Mleaf = Bc * 256;
                int NBL = (Mleaf + 63) / 64; if (NBL > 512) NBL = 512;
                int itersL = (Mleaf + NBL * 64 - 1) / (NBL * 64);
                leaf_mfma<<<NBL, 256, 0, stream>>>(tokens, emb, ws, Ha, toff, Mleaf, itersL);
            }
            for (int l = 7; l >= 0; --l) {
                int M = Bc << l;
                int Mchild = Bc << (l + 1);
                int Mb = (M + 127) / 128;
                int js = 1;
                while (js < 8 && Mb * js < 512) js <<= 1;
                int jcc = 8 / js;
                const short* hC = (l & 1) ? Ha : Hb;
                const float* cC = (l & 1) ? Ca : Cb;
                short* hO = (l & 1) ? Hb : Ha;
                float* cO = (l & 1) ? Cb : Ca;
                int lc = (l == 7) ? 1 : 0;
                int isRoot = (l == 0) ? 1 : 0;
                dim3 grid(Mb * js);
                if (jcc == 4)
                    level_mfma<4><<<grid, 256, 0, stream>>>(tokens, arity, emb, ws, hC, cC, hO, cO,
                                                            rootH, rootC, l, toff, lc, isRoot, M, Mchild, Mb);
                else if (jcc == 2)
                    level_mfma<2><<<grid, 256, 0, stream>>>(tokens, arity, emb, ws, hC, cC, hO, cO,
                                                            rootH, rootC, l, toff, lc, isRoot, M, Mchild, Mb);
                else
                    level_mfma<1><<<grid, 256, 0, stream>>>(tokens, arity, emb, ws, hC, cC, hO, cO,
                                                            rootH, rootC, l, toff, lc, isRoot, M, Mchild, Mb);
            }
        }
    }
    out_kernel<<<128, 256, 0, stream>>>(ws, d_out);
}

// Round 8
// 250.522 us; speedup vs baseline: 3.3085x; 3.3085x over previous
//
#include <hip/hip_runtime.h>
#include <hip/hip_bf16.h>

#define NTOK 511
#define NINT 255

typedef unsigned short u16;
typedef __attribute__((ext_vector_type(8))) short bf16x8;
typedef __attribute__((ext_vector_type(4))) float f32x4;

// ---- workspace layout (float offsets) ----
constexpr int OFF_FLAG = 0;                 // [0] dtype flag
constexpr int OFF_WB   = 4;                 // bf16 weight region
// per jc (72 frags x 512): f 0..15 = Wx(g=f>>2,ks=f&3), 16..31 = Uu, 32..71 = Ub(g=(f-32)>>3,ks=&7)
constexpr int W3B = 294912;                 // leaf W3: [jc][ks] 8x4x512 = 16384
constexpr int WB_ELEMS = 311296;
constexpr int OFF_BIAS = OFF_WB + WB_ELEMS / 2;
constexpr int BW4 = 0, BUB4 = 512, BUB1 = 1024, BUU4 = 1152, B3 = 1664;
constexpr int BIAS_FLOATS = 1792;
constexpr int OFF_ROOT  = OFF_BIAS + BIAS_FLOATS;   // rootH 32768 + rootC 32768 (fp32)
constexpr int OFF_CHUNK = OFF_ROOT + 65536;
constexpr long PER_TREE = 49152;            // floats: Ha bf16 + Hb bf16 + Ca f32 + Cb f32

__device__ __forceinline__ float bf2f(__hip_bfloat16 v) { return __bfloat162float(v); }
__device__ __forceinline__ short f2s(float f) {
    __hip_bfloat16 b = __float2bfloat16(f);
    return *reinterpret_cast<short*>(&b);
}
__device__ __forceinline__ float sigm(float x) { return 1.0f / (1.0f + __expf(-x)); }
__device__ __forceinline__ float tanh_(float x) { return 1.0f - 2.0f / (__expf(2.0f * x) + 1.0f); }

__device__ __forceinline__ float ldf(const void* p, long idx, int isbf) {
    return isbf ? bf2f(((const __hip_bfloat16*)p)[idx]) : ((const float*)p)[idx];
}

__device__ __forceinline__ bf16x8 ldA(const void* p, long idx, int isbf) {
    if (isbf) return *(const bf16x8*)((const short*)p + idx);
    const float* f = (const float*)p + idx;
    float4 a = *(const float4*)f, b = *(const float4*)(f + 4);
    bf16x8 r;
    r[0] = f2s(a.x); r[1] = f2s(a.y); r[2] = f2s(a.z); r[3] = f2s(a.w);
    r[4] = f2s(b.x); r[5] = f2s(b.y); r[6] = f2s(b.z); r[7] = f2s(b.w);
    return r;
}

// async global->LDS 16B
typedef const __attribute__((address_space(1))) unsigned int* gp1_t;
typedef __attribute__((address_space(3))) unsigned int* lp3_t;
__device__ __forceinline__ void stage16(const void* g, void* l) {
    __builtin_amdgcn_global_load_lds((gp1_t)g, (lp3_t)l, 16, 0, 0);
}
// stage one 36 KB half-slice (36 frags x 512 bf16), 256 threads x 9 x 16B
__device__ __forceinline__ void stage36(const short* g, short* l, int t) {
#pragma unroll
    for (int s = 0; s < 9; ++s) {
        int off = (s * 256 + t) * 8;
        stage16(g + off, l + off);
    }
}

// ---- dtype detection ----
__global__ void detect_kernel(const void* W, float* ws) {
    if (threadIdx.x == 0 && blockIdx.x == 0) {
        const u16* u = (const u16*)W;
        int cnt = 0;
        for (int i = 0; i < 128; i += 2) {
            u16 x = u[i];
            int ex = (x >> 7) & 0xff;
            if (x == 0 || (ex >= 96 && ex <= 127)) cnt++;
        }
        ((int*)ws)[0] = (cnt >= 48) ? 1 : 0;
    }
}

// ---- repack: raw weights -> bf16 jc-major frag-linear + fp32 biases ----
__global__ __launch_bounds__(256) void repack_mfma(
    const void* W, const void* bW, const void* Ubin, const void* bUbin,
    const void* Uun, const void* bUun, float* ws)
{
    const int isbf = ((const int*)ws)[0];
    short* wb = (short*)(ws + OFF_WB);
    float* bias = ws + OFF_BIAS;
    int tid = blockIdx.x * blockDim.x + threadIdx.x;
    int nth = gridDim.x * blockDim.x;

    for (int idx = tid; idx < 294912; idx += nth) {
        int e = idx & 511, fjc = idx >> 9;
        int jc = fjc / 72, f = fjc - jc * 72;
        int lane = e >> 3, id8 = e & 7;
        int j = jc * 16 + (lane & 15);
        float v;
        if (f < 16) {
            int g = f >> 2, ks = f & 3;
            int k = ks * 32 + (lane >> 4) * 8 + id8;
            v = ldf(W, (long)g * 16384 + k * 128 + j, isbf);
        } else if (f < 32) {
            int fu = f - 16; int g = fu >> 2, ks = fu & 3;
            int k = ks * 32 + (lane >> 4) * 8 + id8;
            v = ldf(Uun, (long)g * 16384 + k * 128 + j, isbf);
        } else {
            int fb = f - 32; int g = fb >> 3, ks = fb & 7;
            int k = ks * 32 + (lane >> 4) * 8 + id8;
            v = ldf(Ubin, (long)g * 32768 + k * 128 + j, isbf);
        }
        wb[idx] = f2s(v);
    }
    for (int idx = tid; idx < 16384; idx += nth) {
        int e = idx & 511, frag = idx >> 9;
        int jc = frag >> 2, ks = frag & 3;
        int lane = e >> 3, id8 = e & 7;
        int k = ks * 32 + (lane >> 4) * 8 + id8;
        int j = jc * 16 + (lane & 15);
        wb[W3B + idx] = f2s(ldf(W, (long)3 * 16384 + k * 128 + j, isbf));
    }
    for (int j = tid; j < 128; j += nth) {
        float4 b;
        b.x = ldf(bW, 0 * 128 + j, isbf); b.y = ldf(bW, 1 * 128 + j, isbf);
        b.z = ldf(bW, 2 * 128 + j, isbf); b.w = ldf(bW, 3 * 128 + j, isbf);
        ((float4*)(bias + BW4))[j] = b;
        float4 bb;
        bb.x = ldf(bUbin, 0 * 128 + j, isbf); bb.y = ldf(bUbin, 1 * 128 + j, isbf);
        bb.z = ldf(bUbin, 2 * 128 + j, isbf); bb.w = ldf(bUbin, 3 * 128 + j, isbf);
        ((float4*)(bias + BUB4))[j] = bb;
        (bias + BUB1)[j] = ldf(bUbin, 4 * 128 + j, isbf);
        float4 bu;
        bu.x = ldf(bUun, 0 * 128 + j, isbf); bu.y = ldf(bUun, 1 * 128 + j, isbf);
        bu.z = ldf(bUun, 2 * 128 + j, isbf); bu.w = ldf(bUun, 3 * 128 + j, isbf);
        ((float4*)(bias + BUU4))[j] = bu;
        (bias + B3)[j] = ldf(bW, 3 * 128 + j, isbf);
    }
}

#define MFMA(A, B, C) __builtin_amdgcn_mfma_f32_16x16x32_bf16(A, B, C, 0, 0, 0)

// ---- leaf: h = tanh(x @ W3 + b3); W3 in registers, no barriers ----
// h output layout: [jcblk][node][16] bf16
__global__ __launch_bounds__(256, 2) void leaf_mfma(
    const int* __restrict__ tokens, const void* emb, const float* __restrict__ ws,
    short* __restrict__ hOut, int treeOff, int Mtot, int iters)
{
    __shared__ short hst[4][16][132];
    const int t = threadIdx.x;
    const int isbf = ((const int*)ws)[0];
    const int wv = t >> 6, lane = t & 63, quad = lane >> 4, l16 = lane & 15;
    const short* wb = (const short*)(ws + OFF_WB);
    const float* bias = ws + OFF_BIAS;

    bf16x8 bf[32];
#pragma unroll
    for (int f = 0; f < 32; ++f)
        bf[f] = *(const bf16x8*)(wb + W3B + f * 512 + lane * 8);
    float b3v[8];
#pragma unroll
    for (int jc = 0; jc < 8; ++jc) b3v[jc] = (bias + B3)[jc * 16 + l16];

    for (int it = 0; it < iters; ++it) {
        int rb = (blockIdx.x * iters + it) * 64 + wv * 16;
        if (rb >= Mtot) break;
        int p = rb + l16; if (p >= Mtot) p = Mtot - 1;
        int bl = p >> 8, i = p & 255;
        int tk = tokens[(long)(treeOff + bl) * NTOK + 255 + i];
        bf16x8 ax[4];
#pragma unroll
        for (int ks = 0; ks < 4; ++ks)
            ax[ks] = ldA(emb, (long)tk * 128 + ks * 32 + quad * 8, isbf);
        f32x4 acc[8];
#pragma unroll
        for (int jc = 0; jc < 8; ++jc) acc[jc] = {0.f, 0.f, 0.f, 0.f};
#pragma unroll
        for (int jc = 0; jc < 8; ++jc)
#pragma unroll
            for (int ks = 0; ks < 4; ++ks)
                acc[jc] = MFMA(ax[ks], bf[jc * 4 + ks], acc[jc]);
#pragma unroll
        for (int jc = 0; jc < 8; ++jc)
#pragma unroll
            for (int r = 0; r < 4; ++r)
                hst[wv][quad * 4 + r][jc * 16 + l16] = f2s(tanh_(acc[jc][r] + b3v[jc]));
        int nloc = lane >> 2, c0 = (lane & 3) * 4;
        int prow = rb + nloc;
        if (prow < Mtot) {
#pragma unroll
            for (int jcb = 0; jcb < 8; ++jcb) {
                uint2 v = *(const uint2*)&hst[wv][nloc][jcb * 16 + c0];
                *(uint2*)&hOut[((long)jcb * Mtot + prow) * 16 + c0] = v;
            }
        }
    }
}

// ---- internal level: JCC jc per block, double-buffered 36KB half-slice staging,
//      MT m-subtiles per wave (block covers 64*MT nodes) ----
template <int JCC, int MT>
__global__ __launch_bounds__(256, 2) void level_mfma(
    const int* __restrict__ tokens, const int* __restrict__ arity, const void* emb,
    const float* __restrict__ ws, const short* __restrict__ hChild,
    const float* __restrict__ cChild, short* __restrict__ hOut, float* __restrict__ cOut,
    float* __restrict__ rootH, float* __restrict__ rootC,
    int lvl, int treeOff, int leafchild, int isRoot, int Mtot, int Mchild, int NBM)
{
    __shared__ short Bs0[36 * 512];         // 36 KB ping
    __shared__ short Bs1[36 * 512];         // 36 KB pong
    __shared__ short hst[4][MT][16][20];    // wave-private h transpose
    __shared__ int tok[64 * MT];
    __shared__ int ar[64 * MT];

    constexpr int NODES = 64 * MT;
    const int t = threadIdx.x;
    const int isbf = ((const int*)ws)[0];
    const int jsx = blockIdx.x / NBM;       // m-fast block order
    const int mb  = blockIdx.x - jsx * NBM;
    const int jcLo = jsx * JCC;
    const int p0 = mb * NODES;
    const int wv = t >> 6, lane = t & 63, quad = lane >> 4, l16 = lane & 15;
    const int cnt = 1 << lvl, o2 = cnt - 1;
    const short* wb = (const short*)(ws + OFF_WB);
    const float* bias = ws + OFF_BIAS;

    if (t < NODES) {
        int p = p0 + t; if (p >= Mtot) p = Mtot - 1;
        int bl = p >> lvl, i = p - (bl << lvl);
        tok[t] = tokens[(long)(treeOff + bl) * NTOK + o2 + i];
        ar[t]  = arity[(long)(treeOff + bl) * NINT + o2 + i];
    }
    // prologue: stage first half-slice of jcLo into Bs0
    stage36(wb + (long)jcLo * 36864, Bs0, t);
    __syncthreads();   // tok/ar + Bs0 ready

    // A-fragments in registers, loaded once, reused across all JCC jc's
    bf16x8 ax[MT][4], ah[MT][8];
#pragma unroll
    for (int mt = 0; mt < MT; ++mt) {
        int row = wv * (16 * MT) + mt * 16 + l16;
        int p = p0 + row; if (p >= Mtot) p = Mtot - 1;
        int bl = p >> lvl, i = p - (bl << lvl);
        long crow = (long)bl * (cnt << 1) + 2 * i;
        int tk = tok[row];
#pragma unroll
        for (int ks = 0; ks < 4; ++ks)
            ax[mt][ks] = ldA(emb, (long)tk * 128 + ks * 32 + quad * 8, isbf);
#pragma unroll
        for (int ks = 0; ks < 8; ++ks) {
            int k0 = ks * 32 + quad * 8;
            int side = k0 >> 7, kl = k0 & 127;
            ah[mt][ks] = *(const bf16x8*)(hChild +
                ((long)(kl >> 4) * Mchild + crow + side) * 16 + (kl & 15));
        }
    }

    for (int jx = 0; jx < JCC; ++jx) {
        const int jc = jcLo + jx;
        const short* wj = wb + (long)jc * 36864;

        // stage odd half of this jc into Bs1 (overlaps half-0 compute)
        stage36(wj + 36 * 512, Bs1, t);

        // prefetch epilogue c-values for this jc (overlaps MFMA)
        float clv[MT][4], crv[MT][4];
#pragma unroll
        for (int mt = 0; mt < MT; ++mt)
#pragma unroll
        for (int r = 0; r < 4; ++r) {
            if (!leafchild) {
                int pe = p0 + wv * (16 * MT) + mt * 16 + quad * 4 + r;
                if (pe >= Mtot) pe = Mtot - 1;
                int ble = pe >> lvl, ie = pe - (ble << lvl);
                long crowe = (long)ble * (cnt << 1) + 2 * ie;
                clv[mt][r] = cChild[((long)jc * Mchild + crowe) * 16 + l16];
                crv[mt][r] = cChild[((long)jc * Mchild + crowe + 1) * 16 + l16];
            } else { clv[mt][r] = 0.f; crv[mt][r] = 0.f; }
        }

        const int j = jc * 16 + l16;
        const float4 bw = ((const float4*)(bias + BW4))[j];
        const float4 bb = ((const float4*)(bias + BUB4))[j];
        const float  b1 = (bias + BUB1)[j];
        const float4 bu = ((const float4*)(bias + BUU4))[j];

        f32x4 aW[4][MT], aU[4][MT], aB[5][MT];
#pragma unroll
        for (int g = 0; g < 4; ++g)
#pragma unroll
            for (int mt = 0; mt < MT; ++mt) { aW[g][mt] = {0,0,0,0}; aU[g][mt] = {0,0,0,0}; }
#pragma unroll
        for (int g = 0; g < 5; ++g)
#pragma unroll
            for (int mt = 0; mt < MT; ++mt) aB[g][mt] = {0,0,0,0};

        // ---- half 0 from Bs0: Wx (16), Uu (16), Ub g0 ks0..3 (4) ----
#pragma unroll
        for (int f = 0; f < 16; ++f) {
            bf16x8 b = *(const bf16x8*)&Bs0[f * 512 + lane * 8];
#pragma unroll
            for (int mt = 0; mt < MT; ++mt)
                aW[f >> 2][mt] = MFMA(ax[mt][f & 3], b, aW[f >> 2][mt]);
        }
#pragma unroll
        for (int f = 16; f < 32; ++f) {
            bf16x8 b = *(const bf16x8*)&Bs0[f * 512 + lane * 8];
            int g = (f - 16) >> 2, ks = (f - 16) & 3;
#pragma unroll
            for (int mt = 0; mt < MT; ++mt)
                aU[g][mt] = MFMA(ah[mt][ks], b, aU[g][mt]);
        }
#pragma unroll
        for (int f = 32; f < 36; ++f) {
            bf16x8 b = *(const bf16x8*)&Bs0[f * 512 + lane * 8];
#pragma unroll
            for (int mt = 0; mt < MT; ++mt)
                aB[0][mt] = MFMA(ah[mt][f - 32], b, aB[0][mt]);
        }
        __syncthreads();   // all waves done with Bs0; Bs1 stage drained

        // stage next jc's even half into Bs0 (overlaps half-1 compute)
        if (jx + 1 < JCC)
            stage36(wj + 72 * 512, Bs0, t);

        // ---- half 1 from Bs1: Ub g0 ks4..7, g1..g4 ----
#pragma unroll
        for (int f = 36; f < 72; ++f) {
            bf16x8 b = *(const bf16x8*)&Bs1[(f - 36) * 512 + lane * 8];
            int fb = f - 32, g = fb >> 3, ks = fb & 7;
#pragma unroll
            for (int mt = 0; mt < MT; ++mt)
                aB[g][mt] = MFMA(ah[mt][ks], b, aB[g][mt]);
        }

        // ---- epilogue ----
#pragma unroll
        for (int mt = 0; mt < MT; ++mt) {
#pragma unroll
            for (int r = 0; r < 4; ++r) {
                int ml = wv * (16 * MT) + mt * 16 + quad * 4 + r;
                int p = p0 + ml;
                bool val = (p < Mtot);
                int pc = val ? p : Mtot - 1;
                int bl = pc >> lvl, i = pc - (bl << lvl);
                bool bin = (ar[ml] == 1);
                float w0 = aW[0][mt][r] + bw.x;
                float w1 = aW[1][mt][r] + bw.y;
                float w2 = aW[2][mt][r] + bw.z;
                float w3 = aW[3][mt][r] + bw.w;
                float pi, pf, po, pu;
                if (bin) { pi = w0 + aB[0][mt][r] + bb.x; pf = w1 + aB[1][mt][r] + bb.y;
                           po = w2 + aB[3][mt][r] + bb.w; pu = w3 + aB[4][mt][r] + b1; }
                else     { pi = w0 + aU[0][mt][r] + bu.x; pf = w1 + aU[1][mt][r] + bu.y;
                           po = w2 + aU[2][mt][r] + bu.z; pu = w3 + aU[3][mt][r] + bu.w; }
                float cl = clv[mt][r];
                float cr = bin ? crv[mt][r] : 0.f;
                float frv = bin ? sigm(w1 + aB[2][mt][r] + bb.z) : 0.f;
                float ig = sigm(pi), fg = sigm(pf), og = sigm(po), ug = tanh_(pu);
                float c = ig * ug + fg * cl + frv * cr;
                float h = og * tanh_(c);
                if (isRoot) {
                    if (val) {
                        rootH[(long)(treeOff + bl) * 128 + j] = h;
                        rootC[(long)(treeOff + bl) * 128 + j] = c;
                    }
                } else {
                    if (val) cOut[((long)jc * Mtot + pc) * 16 + l16] = c;
                    hst[wv][mt][quad * 4 + r][l16] = f2s(h);
                }
            }
        }
        if (!isRoot) {
            int nloc = lane >> 2, c0 = (lane & 3) * 4;
#pragma unroll
            for (int mt = 0; mt < MT; ++mt) {
                int prow = p0 + wv * (16 * MT) + mt * 16 + nloc;
                if (prow < Mtot) {
                    uint2 v = *(const uint2*)&hst[wv][mt][nloc][c0];
                    *(uint2*)&hOut[((long)jc * Mtot + prow) * 16 + c0] = v;
                }
            }
        }
        __syncthreads();   // Bs1 free for restage; Bs0 (next jc) drained
    }
}

// ---- output: rootH/rootC fp32 -> d_out ----
__global__ __launch_bounds__(256) void out_kernel(const float* ws, void* out)
{
    const int isbf = ((const int*)ws)[0];
    const float* rootH = ws + OFF_ROOT;
    const float* rootC = rootH + 32768;
    int t = blockIdx.x * 256 + threadIdx.x;
    float h = rootH[t], c = rootC[t];
    if (isbf) {
        ((__hip_bfloat16*)out)[t]         = __float2bfloat16(h);
        ((__hip_bfloat16*)out)[32768 + t] = __float2bfloat16(c);
    } else {
        ((float*)out)[t]         = h;
        ((float*)out)[32768 + t] = c;
    }
}

extern "C" void kernel_launch(void* const* d_in, const int* in_sizes, int n_in,
                              void* d_out, int out_size, void* d_ws, size_t ws_size,
                              hipStream_t stream)
{
    const int* tokens = (const int*)d_in[0];
    const int* arity  = (const int*)d_in[1];
    const void* emb   = d_in[2];
    const void* W     = d_in[3];
    const void* bW    = d_in[4];
    const void* Ubin  = d_in[5];
    const void* bUbin = d_in[6];
    const void* Uun   = d_in[7];
    const void* bUun  = d_in[8];

    float* ws = (float*)d_ws;

    int Bc = 256;
    while (Bc > 1 && (size_t)(OFF_CHUNK + Bc * PER_TREE) * 4 > ws_size) Bc >>= 1;
    const int nCh = 256 / Bc;

    detect_kernel<<<1, 64, 0, stream>>>(W, ws);
    repack_mfma<<<128, 256, 0, stream>>>(W, bW, Ubin, bUbin, Uun, bUun, ws);

    short* Ha = (short*)(ws + OFF_CHUNK);
    short* Hb = Ha + (long)Bc * 32768;
    float* Ca = (float*)(Hb + (long)Bc * 16384);
    float* Cb = Ca + (long)Bc * 8192;
    float* rootH = ws + OFF_ROOT;
    float* rootC = rootH + 32768;

    for (int cidx = 0; cidx < nCh; ++cidx) {
        int toff = cidx * Bc;
        {
            int Mleaf = Bc * 256;
            int NBL = (Mleaf + 63) / 64; if (NBL > 512) NBL = 512;
            int itersL = (Mleaf + NBL * 64 - 1) / (NBL * 64);
            leaf_mfma<<<NBL, 256, 0, stream>>>(tokens, emb, ws, Ha, toff, Mleaf, itersL);
        }
        for (int l = 7; l >= 0; --l) {
            int M = Bc << l;
            int Mchild = Bc << (l + 1);
            const short* hC = (l & 1) ? Ha : Hb;
            const float* cC = (l & 1) ? Ca : Cb;
            short* hO = (l & 1) ? Hb : Ha;
            float* cO = (l & 1) ? Cb : Ca;
            int lc = (l == 7) ? 1 : 0;
            int isRoot = (l == 0) ? 1 : 0;
            if (l >= 5) {
                int Mb = (M + 127) / 128;
                int js = 1;
                while (js < 8 && Mb * js < 512) js <<= 1;
                int jcc = 8 / js;
                dim3 grid(Mb * js);
                if (jcc == 8)
                    level_mfma<8, 2><<<grid, 256, 0, stream>>>(tokens, arity, emb, ws, hC, cC, hO, cO,
                                                               rootH, rootC, l, toff, lc, isRoot, M, Mchild, Mb);
                else if (jcc == 4)
                    level_mfma<4, 2><<<grid, 256, 0, stream>>>(tokens, arity, emb, ws, hC, cC, hO, cO,
                                                               rootH, rootC, l, toff, lc, isRoot, M, Mchild, Mb);
                else if (jcc == 2)
                    level_mfma<2, 2><<<grid, 256, 0, stream>>>(tokens, arity, emb, ws, hC, cC, hO, cO,
                                                               rootH, rootC, l, toff, lc, isRoot, M, Mchild, Mb);
                else
                    level_mfma<1, 2><<<grid, 256, 0, stream>>>(tokens, arity, emb, ws, hC, cC, hO, cO,
                                                               rootH, rootC, l, toff, lc, isRoot, M, Mchild, Mb);
            } else {
                int Mb = (M + 63) / 64;
                dim3 grid(Mb * 8);
                level_mfma<1, 1><<<grid, 256, 0, stream>>>(tokens, arity, emb, ws, hC, cC, hO, cO,
                                                           rootH, rootC, l, toff, lc, isRoot, M, Mchild, Mb);
            }
        }
    }
    out_kernel<<<128, 256, 0, stream>>>(ws, d_out);
}